// Round 12
// baseline (19388.406 us; speedup 1.0000x reference)
//
#include <hip/hip_runtime.h>

typedef _Float16 f16;
typedef __attribute__((ext_vector_type(8))) _Float16 half8;
typedef __attribute__((ext_vector_type(4))) float f32x4;
typedef __attribute__((ext_vector_type(4))) unsigned int uint4v;

#define B_   512
#define T_   256
#define TT_  320
#define KB0  33
#define KBR  64
#define NSLOT 12   // small kernel: ring of 3 rounds x 4 slabs; 12 x 12KB = 144KB LDS

// LLVM AMDGPU CPol (gfx950): GLC=1(SC0), SLC=2(NT), DLC=4, SCC=16(SC1)
#define AUX_COHERENT 17   // SC0|SC1: read at coherence point, no L2 allocate (R6-proven)

struct PP {
  const f16* Wt[4];
  f16* xh[4][2];
  float* cst;         // [4][512][1024] fp32 cell state (zeroed per call)
  const float* bias;
  const float* input;
  const float* cov;
  const float* Wl;
  const float* blp;
  float* out;
  unsigned* cnt;      // [259] global diagonal-stage counters (xh0 slab-0 dead zone)
};

__device__ __forceinline__ void gload16(const void* g, void* l) {
  __builtin_amdgcn_global_load_lds((const __attribute__((address_space(1))) void*)g,
                                   (__attribute__((address_space(3))) void*)l,
                                   16, 0, 0);
}
__device__ __forceinline__ void gload16c(const void* g, void* l) {  // coherent (bypass L2)
  __builtin_amdgcn_global_load_lds((const __attribute__((address_space(1))) void*)g,
                                   (__attribute__((address_space(3))) void*)l,
                                   16, 0, AUX_COHERENT);
}

__device__ __forceinline__ float sigf(float x) {
  return __builtin_amdgcn_rcpf(1.f + __builtin_amdgcn_exp2f(-1.44269504f * x));
}
__device__ __forceinline__ float tanhf_(float x) {
  return 2.f * __builtin_amdgcn_rcpf(1.f + __builtin_amdgcn_exp2f(-2.88539008f * x)) - 1.f;
}

// fragment-ordered xh address: slab (k/32) of [512 rows x 32 k], tile layout [m/16][lane][8]
__device__ __forceinline__ int haddr(int k, int m) {
  return (k >> 5) * 16384 + (m >> 4) * 512 + ((m & 15) + ((k & 31) >> 3) * 16) * 8 + (k & 7);
}

// counted wait + raw barrier fused in ONE asm so nothing schedules between them.
#define WAITBAR(vm) asm volatile("s_waitcnt vmcnt(" #vm ") lgkmcnt(0)\n\ts_barrier" ::: "memory")

// ============================================================================
// PERSISTENT conditioning kernel (R6 memory protocol, R10 geometry) with SPLIT
// A/B LDS rings — the R10 fix. B (weights) is L2-hot in persistent mode
// (~250cyc): ring of 3 x 16KB, lookahead 2. A (h, coherent ~900-2000cyc):
// ring of 12 x 8KB, lookahead 10. Per-round stage issue: 1 A-gload + 1 B-stage
// (2 gloads) = 3 vm-instr/wave/round -> steady WAITBAR(3); rounds 0/1 use the
// issue-order-counted constants below. Clamped phantom stages in the tail keep
// counts constant (phantoms land in dead slots). B(0),B(1) of the NEXT step are
// prefetched after the release, overlapping the gate spin (B is gate-independent).
// s_setprio(1) wraps the MFMA cluster (T5: this schedule has wave role-split).
// ============================================================================
__global__ __launch_bounds__(512, 1) void lstm_cond(PP P)
{
  __shared__ f16 lds_a[12][4096];   // 96KB: A K32-slabs (M128 x 32k)
  __shared__ f16 lds_b[3][8192];    // 48KB: B K32-slabs (4 panels = 256 gate-cols)
  const int tid = threadIdx.x;
  const int ln = tid & 63, w = tid >> 6;
  const int mg = w >> 2, ng = w & 3;
  const int cid = blockIdx.x >> 6, bb = blockIdx.x & 63;
  const int mb2 = bb >> 4, nb2 = bb & 15;
  const int m0 = mb2 * 128;
  const int l = cid;

  const f16* __restrict__ Wt = P.Wt[l];
  const int KB   = (l == 0) ? KB0 : KBR;
  const int koff = (l == 0) ? 32 : 1024;
  const float* __restrict__ bias4 = P.bias + l * 4096;
  float* __restrict__ cst = P.cst + (size_t)l * 524288;
  const int col = (nb2 * 4 + ng) * 16 + (ln & 15);
  const float bi  = bias4[col];
  const float bff = bias4[1024 + col];
  const float bgg = bias4[2048 + col];
  const float bo  = bias4[3072 + col];
  const float wl  = (l == 3) ? P.Wl[col] : 0.f;

  auto stageB = [&](int slot, int kb) {     // 2 vm-instr; plain cached (L2-hot weights)
    const int e0 = tid, e1 = tid + 512;
    gload16(Wt + ((size_t)((nb2 * 4 + (e0 >> 8)) * KB + kb)) * 2048 + (e0 & 255) * 8,
            &lds_b[slot][e0 * 8]);
    gload16(Wt + ((size_t)((nb2 * 4 + (e1 >> 8)) * KB + kb)) * 2048 + (e1 & 255) * 8,
            &lds_b[slot][e1 * 8]);
  };

  // initial pre-gate B prefetch: step 0 is active only for cell 0
  if (l == 0) { stageB(0, 0); stageB(1, 1); }

  for (int s = 0; s <= 258; ++s) {
    const int t = s - l;

    // ---- gate: all 256 blocks finished diagonal s-1 (relaxed agent; no fence)
    if (s > 0) {
      if (tid == 0) {
        while (__hip_atomic_load(&P.cnt[s - 1], __ATOMIC_RELAXED,
                                 __HIP_MEMORY_SCOPE_AGENT) < 256u)
          __builtin_amdgcn_s_sleep(8);
      }
      __syncthreads();
    }

    if (t >= 0 && t < T_) {
      const int p = t & 1, q = p ^ 1;
      const f16* __restrict__ src = P.xh[l][p];
      f16* __restrict__ selfd     = P.xh[l][q];
      f16* __restrict__ nextd     = (l < 3) ? P.xh[l + 1][p] : nullptr;

      // init out[b][t] = bl (agent store; cell3's atomics come 3 stages later)
      if (l == 0 && nb2 == 0 && tid < 128)
        __hip_atomic_store(&P.out[(size_t)(m0 + tid) * TT_ + t], P.blp[0],
                           __ATOMIC_RELAXED, __HIP_MEMORY_SCOPE_AGENT);

      auto stageA = [&](int slot, int kb) {  // 1 vm-instr (or ds_write for l0 slab0)
        if (l == 0 && kb == 0) {
          // x-columns (8 real + 24 zero pad) in fragment order (ds_write)
          int mf = tid >> 6, r = ln & 15, kgrp = ln >> 4;
          int brow = m0 + mf * 16 + r;
          half8 v;
          #pragma unroll
          for (int z = 0; z < 8; ++z) v[z] = (f16)0.f;
          if (kgrp == 0) {
            v[0] = (f16)P.input[brow * T_ + t];
            const float* cp = P.cov + ((size_t)brow * TT_ + t) * 7;
            #pragma unroll
            for (int z = 1; z < 8; ++z) v[z] = (f16)cp[z - 1];
          }
          *(half8*)&lds_a[slot][tid * 8] = v;
        } else {
          gload16c(src + (size_t)kb * 16384 + mb2 * 4096 + tid * 8, &lds_a[slot][tid * 8]);
        }
      };

      f32x4 acc[4][4];
      #pragma unroll
      for (int m = 0; m < 4; ++m)
        #pragma unroll
        for (int g = 0; g < 4; ++g) { acc[m][g][0]=0.f; acc[m][g][1]=0.f; acc[m][g][2]=0.f; acc[m][g][3]=0.f; }

      // post-gate A prologue: slots 0..9 (B(0),B(1) already in flight pre-gate)
      #pragma unroll
      for (int kb = 0; kb < 10; ++kb) stageA(kb, kb);

      for (int i = 0; i < KB; ++i) {
        // waits (issue-order-counted; see header comment):
        //   round 0: l==0 -> 11 (after B0: B1=2 + 9 A-gloads), l>0 -> 9 (after A0)
        //   round 1: 11 (after A1: A2..9=8 + round0's 3)
        //   round >=2: 3 (after B(i) issued at round i-2: round i-1's 3)
        if (i == 0)      { if (l == 0) { WAITBAR(11); } else { WAITBAR(9); } }
        else if (i == 1) { WAITBAR(11); }
        else             { WAITBAR(3); }
        const half8* A  = (const half8*)&lds_a[i % 12][0];
        const half8* Bp = (const half8*)&lds_b[i % 3][0];
        half8 a[4], b[4];
        #pragma unroll
        for (int m = 0; m < 4; ++m) a[m] = A[(mg * 4 + m) * 64 + ln];
        #pragma unroll
        for (int g = 0; g < 4; ++g) b[g] = Bp[ng * 256 + g * 64 + ln];
        // issue next stages (clamped phantoms keep per-round vm counts constant;
        // phantom targets are dead slots, overwritten after the end-of-step drain)
        int ka = i + 10; if (ka >= KB) ka = KB - 1;
        stageA((i + 10) % 12, ka);
        int kbb = i + 2; if (kbb >= KB) kbb = KB - 1;
        stageB((i + 2) % 3, kbb);
        __builtin_amdgcn_s_setprio(1);
        #pragma unroll
        for (int m = 0; m < 4; ++m)
          #pragma unroll
          for (int g = 0; g < 4; ++g)
            acc[m][g] = __builtin_amdgcn_mfma_f32_16x16x32_f16(a[m], b[g], acc[m][g], 0, 0, 0);
        __builtin_amdgcn_s_setprio(0);
      }
      WAITBAR(0);                            // drain phantoms before slot reuse

      // ---- epilogue: wave (mg,ng) owns rows mg*64..+63, panel ng (full-K, no splitK)
      #pragma unroll
      for (int m = 0; m < 4; ++m) {
        const int rowb = m0 + (mg * 4 + m) * 16 + (ln >> 4) * 4;
        #pragma unroll
        for (int r = 0; r < 4; ++r) {
          const int row = rowb + r;
          float gi = acc[m][0][r] + bi;
          float gf = acc[m][1][r] + bff;
          float gg = acc[m][2][r] + bgg;
          float go = acc[m][3][r] + bo;
          float* cp = cst + (size_t)row * 1024 + col;   // block-private, L2-hot
          float cn = sigf(gf) * (*cp) + sigf(gi) * tanhf_(gg);
          float h  = sigf(go) * tanhf_(cn);
          *cp = cn;
          f16 hh = (f16)h;
          unsigned short hbits = __builtin_bit_cast(unsigned short, hh);
          __hip_atomic_store((unsigned short*)&selfd[haddr(koff + col, row)], hbits,
                             __ATOMIC_RELAXED, __HIP_MEMORY_SCOPE_AGENT);
          if (l < 3) {
            __hip_atomic_store((unsigned short*)&nextd[haddr(col, row)], hbits,
                               __ATOMIC_RELAXED, __HIP_MEMORY_SCOPE_AGENT);
          } else {
            float val = h * wl;
            val += __shfl_xor(val, 1);
            val += __shfl_xor(val, 2);
            val += __shfl_xor(val, 4);
            val += __shfl_xor(val, 8);
            if ((ln & 15) == 0) atomicAdd(P.out + (size_t)row * TT_ + t, val);
          }
        }
      }
    }

    // ---- release: __syncthreads() drains each wave's stores (vmcnt0 before
    // s_barrier => agent stores acked at coherence point), then signal; then
    // prefetch next step's B(0),B(1) so their latency overlaps the gate spin.
    __syncthreads();
    if (tid == 0)
      __hip_atomic_fetch_add(&P.cnt[s], 1u, __ATOMIC_RELAXED, __HIP_MEMORY_SCOPE_AGENT);
    const int tn = (s + 1) - l;
    if (tn >= 0 && tn < T_) { stageB(0, 0); stageB(1, 1); }
  }
}

// ============================================================================
// Small-tile kernel (R4/R8-proven): serial FUTURE phase (t >= 256), 1 cell/dispatch.
// ============================================================================
__global__ __launch_bounds__(512) void lstm_cells(PP P, int d, int lbeg, int lend, int tlim)
{
  __shared__ f16 lds[NSLOT][6144];
  const int tid = threadIdx.x;
  const int ln = tid & 63, w = tid >> 6;
  const int mg = w & 1, kg = w >> 1;
  const int nb = blockIdx.x & 63, mb = blockIdx.x >> 6;
  const int m0 = mb * 128, n0 = nb * 16;

  for (int l = lbeg; l <= lend; ++l) {
    const int t = d - l;
    if (t < 0 || t >= tlim) continue;

    const int p = t & 1, q = p ^ 1;
    const f16* __restrict__ Wt = P.Wt[l];
    const int KB   = (l == 0) ? KB0 : KBR;
    const int mode = (l == 0) ? 0 : ((l == 3) ? 2 : 1);
    const int koff = (l == 0) ? 32 : 1024;
    const f16* __restrict__ src   = P.xh[l][p];
    f16* __restrict__ selfd       = P.xh[l][q];
    f16* __restrict__ nextd       = (l < 3) ? P.xh[l + 1][p] : nullptr;
    const float* __restrict__ bias4 = P.bias + l * 4096;
    float* __restrict__ cst = P.cst + (size_t)l * 524288;

    if (mode == 0 && nb == 0 && tid < 128) P.out[(size_t)(m0 + tid) * TT_ + t] = P.blp[0];

    auto stage_slab = [&](int slot, int kb) {
      if (mode == 0 && kb == 0) {
        int mf = tid >> 6, r = ln & 15, kgrp = ln >> 4;
        int brow = m0 + mf * 16 + r;
        half8 v;
        #pragma unroll
        for (int j = 0; j < 8; ++j) v[j] = (f16)0.f;
        if (kgrp == 0) {
          float x0 = (t < T_) ? P.input[brow * T_ + t] : P.out[(size_t)brow * TT_ + (t - 1)];
          v[0] = (f16)x0;
          const float* cp = P.cov + ((size_t)brow * TT_ + t) * 7;
          #pragma unroll
          for (int j = 1; j < 8; ++j) v[j] = (f16)cp[j - 1];
        }
        *(half8*)&lds[slot][tid * 8] = v;
      } else {
        gload16(src + (size_t)kb * 16384 + mb * 4096 + tid * 8, &lds[slot][tid * 8]);
      }
      if (tid < 256)
        gload16(Wt + ((size_t)(nb * KB + kb)) * 2048 + tid * 8, &lds[slot][4096 + tid * 8]);
    };
    auto stage_round = [&](int r) {
      int base = (r % 3) * 4;
      #pragma unroll
      for (int j = 0; j < 4; ++j) {
        int kb = r * 4 + j;
        if (kb >= KB) kb = KB - 1;
        stage_slab(base + j, kb);
      }
    };

    f32x4 acc[4][4];
    #pragma unroll
    for (int m = 0; m < 4; ++m)
      #pragma unroll
      for (int g = 0; g < 4; ++g) { acc[m][g][0]=0.f; acc[m][g][1]=0.f; acc[m][g][2]=0.f; acc[m][g][3]=0.f; }

    const int R = (KB + 3) >> 2;
    stage_round(0); stage_round(1);
    for (int i = 0; i < R; ++i) {
      if (i < R - 1) { if (w < 4) WAITBAR(8); else WAITBAR(4); }
      else           { WAITBAR(0); }
      const int kb = i * 4 + kg;
      const int slot = (i % 3) * 4 + kg;
      const half8* A  = (const half8*)&lds[slot][0];
      const half8* Bp = (const half8*)&lds[slot][4096];
      const bool live = (kb < KB);
      half8 a0, a1, a2, a3, b0, b1, b2, b3;
      if (live) {
        a0 = A[(mg * 4 + 0) * 64 + ln];
        a1 = A[(mg * 4 + 1) * 64 + ln];
        a2 = A[(mg * 4 + 2) * 64 + ln];
        a3 = A[(mg * 4 + 3) * 64 + ln];
        b0 = Bp[ln]; b1 = Bp[64 + ln]; b2 = Bp[128 + ln]; b3 = Bp[192 + ln];
      }
      if (i + 2 < R) stage_round(i + 2);
      if (live) {
        acc[0][0] = __builtin_amdgcn_mfma_f32_16x16x32_f16(a0, b0, acc[0][0], 0, 0, 0);
        acc[0][1] = __builtin_amdgcn_mfma_f32_16x16x32_f16(a0, b1, acc[0][1], 0, 0, 0);
        acc[0][2] = __builtin_amdgcn_mfma_f32_16x16x32_f16(a0, b2, acc[0][2], 0, 0, 0);
        acc[0][3] = __builtin_amdgcn_mfma_f32_16x16x32_f16(a0, b3, acc[0][3], 0, 0, 0);
        acc[1][0] = __builtin_amdgcn_mfma_f32_16x16x32_f16(a1, b0, acc[1][0], 0, 0, 0);
        acc[1][1] = __builtin_amdgcn_mfma_f32_16x16x32_f16(a1, b1, acc[1][1], 0, 0, 0);
        acc[1][2] = __builtin_amdgcn_mfma_f32_16x16x32_f16(a1, b2, acc[1][2], 0, 0, 0);
        acc[1][3] = __builtin_amdgcn_mfma_f32_16x16x32_f16(a1, b3, acc[1][3], 0, 0, 0);
        acc[2][0] = __builtin_amdgcn_mfma_f32_16x16x32_f16(a2, b0, acc[2][0], 0, 0, 0);
        acc[2][1] = __builtin_amdgcn_mfma_f32_16x16x32_f16(a2, b1, acc[2][1], 0, 0, 0);
        acc[2][2] = __builtin_amdgcn_mfma_f32_16x16x32_f16(a2, b2, acc[2][2], 0, 0, 0);
        acc[2][3] = __builtin_amdgcn_mfma_f32_16x16x32_f16(a2, b3, acc[2][3], 0, 0, 0);
        acc[3][0] = __builtin_amdgcn_mfma_f32_16x16x32_f16(a3, b0, acc[3][0], 0, 0, 0);
        acc[3][1] = __builtin_amdgcn_mfma_f32_16x16x32_f16(a3, b1, acc[3][1], 0, 0, 0);
        acc[3][2] = __builtin_amdgcn_mfma_f32_16x16x32_f16(a3, b2, acc[3][2], 0, 0, 0);
        acc[3][3] = __builtin_amdgcn_mfma_f32_16x16x32_f16(a3, b3, acc[3][3], 0, 0, 0);
      }
    }

    __syncthreads();
    float* red = (float*)&lds[0][0];
    #pragma unroll
    for (int m = 0; m < 4; ++m)
      #pragma unroll
      for (int g = 0; g < 4; ++g)
        *(f32x4*)&red[w * 4096 + (m * 4 + g) * 256 + ln * 4] = acc[m][g];
    __syncthreads();
    f32x4 facc[4];
    #pragma unroll
    for (int g = 0; g < 4; ++g) { facc[g][0]=0.f; facc[g][1]=0.f; facc[g][2]=0.f; facc[g][3]=0.f; }
    const int mgw = w >> 2, mlw = w & 3;
    #pragma unroll
    for (int kg2 = 0; kg2 < 4; ++kg2) {
      const int wsrc = kg2 * 2 + mgw;
      #pragma unroll
      for (int g = 0; g < 4; ++g) {
        f32x4 pv = *(const f32x4*)&red[wsrc * 4096 + (mlw * 4 + g) * 256 + ln * 4];
        facc[g][0] += pv[0]; facc[g][1] += pv[1]; facc[g][2] += pv[2]; facc[g][3] += pv[3];
      }
    }
    __syncthreads();

    const int col = n0 + (ln & 15);
    const int rowb = m0 + w * 16 + (ln >> 4) * 4;
    const float bi  = bias4[col];
    const float bff = bias4[1024 + col];
    const float bgg = bias4[2048 + col];
    const float bo  = bias4[3072 + col];
    const float wl  = (mode == 2) ? P.Wl[col] : 0.f;
    #pragma unroll
    for (int r = 0; r < 4; ++r) {
      const int row = rowb + r;
      float gi = facc[0][r] + bi;
      float gf = facc[1][r] + bff;
      float gg = facc[2][r] + bgg;
      float go = facc[3][r] + bo;
      float* cp = cst + (size_t)row * 1024 + col;
      float cn = sigf(gf) * (*cp) + sigf(gi) * tanhf_(gg);
      float h  = sigf(go) * tanhf_(cn);
      *cp = cn;
      f16 hh = (f16)h;
      selfd[haddr(koff + col, row)] = hh;
      if (mode != 2) {
        nextd[haddr(col, row)] = hh;
      } else {
        float val = h * wl;
        val += __shfl_xor(val, 1);
        val += __shfl_xor(val, 2);
        val += __shfl_xor(val, 4);
        val += __shfl_xor(val, 8);
        if ((ln & 15) == 0) atomicAdd(P.out + (size_t)row * TT_ + t, val);
      }
    }
  }
}

__global__ void zero_ws(uint4v* pz, int n)   // zero xh (incl. cnt dead-zone) + cell state
{
  int i = blockIdx.x * 256 + threadIdx.x;
  if (i < n) { uint4v z; z[0] = 0u; z[1] = 0u; z[2] = 0u; z[3] = 0u; pz[i] = z; }
}

__global__ void pack_weights(const float* __restrict__ Wih0, const float* __restrict__ Whh0,
                             const float* __restrict__ Wihr, const float* __restrict__ Whhr,
                             f16* __restrict__ Wt0, f16* __restrict__ Wt1,
                             f16* __restrict__ Wt2, f16* __restrict__ Wt3)
{
  const int layer = blockIdx.y;
  const size_t e = (size_t)blockIdx.x * 256 + threadIdx.x;
  const int KB = layer ? KBR : KB0;
  if (e >= (size_t)64 * KB * 2048) return;
  const int panel = (int)(e >> 11), win = (int)(e & 2047);
  const int g = win >> 9, lane = (win >> 3) & 63, j = win & 7;
  const int nb = panel / KB, kb = panel - nb * KB;
  const int n = nb * 16 + (lane & 15);
  const int k = kb * 32 + (lane >> 4) * 8 + j;
  const int jr = g * 1024 + n;                       // row in [4H][*] weight (gate-major)
  float v;
  if (layer == 0) {
    if (k < 8)       v = Wih0[jr * 8 + k];
    else if (k < 32) v = 0.f;
    else             v = Whh0[(size_t)jr * 1024 + (k - 32)];
  } else {
    const size_t base = (size_t)(layer - 1) * 4096 * 1024 + (size_t)jr * 1024;
    v = (k < 1024) ? Wihr[base + k] : Whhr[base + (k - 1024)];
  }
  f16 hv = (f16)v;
  if      (layer == 0) Wt0[e] = hv;
  else if (layer == 1) Wt1[e] = hv;
  else if (layer == 2) Wt2[e] = hv;
  else                 Wt3[e] = hv;
}

__global__ void pack_bias(const float* __restrict__ bih0, const float* __restrict__ bhh0,
                          const float* __restrict__ bihr, const float* __restrict__ bhhr,
                          float* __restrict__ bias)
{
  const int idx = blockIdx.x * 256 + threadIdx.x;    // 16384 = 4 layers x 4096
  const int lyr = idx >> 12, j = idx & 4095;
  bias[idx] = (lyr == 0) ? (bih0[j] + bhh0[j])
                         : (bihr[(lyr - 1) * 4096 + j] + bhhr[(lyr - 1) * 4096 + j]);
}

extern "C" void kernel_launch(void* const* d_in, const int* in_sizes, int n_in,
                              void* d_out, int out_size, void* d_ws, size_t ws_size,
                              hipStream_t stream)
{
  const float* input = (const float*)d_in[0];
  const float* cov   = (const float*)d_in[1];
  const float* Wih0  = (const float*)d_in[2];
  const float* Whh0  = (const float*)d_in[3];
  const float* bih0  = (const float*)d_in[4];
  const float* bhh0  = (const float*)d_in[5];
  const float* Wihr  = (const float*)d_in[6];
  const float* Whhr  = (const float*)d_in[7];
  const float* bihr  = (const float*)d_in[8];
  const float* bhhr  = (const float*)d_in[9];
  const float* Wl    = (const float*)d_in[10];
  const float* blp   = (const float*)d_in[11];
  float* out = (float*)d_out;
  char* ws = (char*)d_ws;

  // workspace layout (bytes): unchanged from R8-R11. cnt[259] lives in xh0[0]'s
  // slab-0 dead zone (bytes [0,32768) never touched by cells: layer0 k-slab 0 is
  // LDS-generated; h-writes start at koff=32). zero_ws clears it each call.
  const size_t XH0 = 1081344, XHR = 2097152;
  PP Pv;
  Pv.xh[0][0] = (f16*)(ws);            Pv.xh[0][1] = (f16*)(ws + XH0);
  Pv.xh[1][0] = (f16*)(ws + 2162688);  Pv.xh[1][1] = (f16*)(ws + 2162688 + XHR);
  Pv.xh[2][0] = (f16*)(ws + 6356992);  Pv.xh[2][1] = (f16*)(ws + 6356992 + XHR);
  Pv.xh[3][0] = (f16*)(ws + 10551296); Pv.xh[3][1] = (f16*)(ws + 10551296 + XHR);
  Pv.cst     = (float*)(ws + 14745600);
  Pv.cnt     = (unsigned*)(ws);
  float* bias = (float*)(ws + 23134208);
  f16* Wt0 = (f16*)(ws + 23199744);
  f16* Wt1 = (f16*)(ws + 31850496);
  f16* Wt2 = (f16*)(ws + 48627712);
  f16* Wt3 = (f16*)(ws + 65404928);
  Pv.Wt[0] = Wt0; Pv.Wt[1] = Wt1; Pv.Wt[2] = Wt2; Pv.Wt[3] = Wt3;
  Pv.bias = bias; Pv.input = input; Pv.cov = cov;
  Pv.Wl = Wl; Pv.blp = blp; Pv.out = out;

  pack_weights<<<dim3(32768, 4), 256, 0, stream>>>(Wih0, Whh0, Wihr, Whhr, Wt0, Wt1, Wt2, Wt3);
  pack_bias<<<64, 256, 0, stream>>>(bih0, bhh0, bihr, bhhr, bias);
  zero_ws<<<5648, 256, 0, stream>>>((uint4v*)ws, 23134208 / 16);

  // Conditioning (t < 256): ONE persistent cooperative kernel, split A/B rings.
  void* args[] = { &Pv };
  hipLaunchCooperativeKernel(reinterpret_cast<void*>(&lstm_cond),
                             dim3(256), dim3(512), args, 0, stream);

  // Future (t >= 256): out-feedback serializes; one small-tile cell per dispatch.
  for (int t = T_; t < TT_; ++t)
    for (int l = 0; l < 4; ++l)
      lstm_cells<<<256, 512, 0, stream>>>(Pv, t + l, l, l, TT_);
}

// Round 13
// 14962.991 us; speedup vs baseline: 1.2958x; 1.2958x over previous
//
#include <hip/hip_runtime.h>

typedef _Float16 f16;
typedef __attribute__((ext_vector_type(8))) _Float16 half8;
typedef __attribute__((ext_vector_type(4))) float f32x4;
typedef __attribute__((ext_vector_type(4))) unsigned int uint4v;

#define B_   512
#define T_   256
#define TT_  320
#define KB0  33
#define KBR  64
#define NSLOT 12   // small kernel: ring of 3 rounds x 4 slabs; 12 x 12KB = 144KB LDS

struct PP {
  const f16* Wt[4];
  f16* xh[4][2];
  float* cst;         // [4][512][1024] fp32 cell state (zeroed per call)
  const float* bias;
  const float* input;
  const float* cov;
  const float* Wl;
  const float* blp;
  float* out;
};

__device__ __forceinline__ void gload16(const void* g, void* l) {
  __builtin_amdgcn_global_load_lds((const __attribute__((address_space(1))) void*)g,
                                   (__attribute__((address_space(3))) void*)l,
                                   16, 0, 0);
}

__device__ __forceinline__ float sigf(float x) {
  return __builtin_amdgcn_rcpf(1.f + __builtin_amdgcn_exp2f(-1.44269504f * x));
}
__device__ __forceinline__ float tanhf_(float x) {
  return 2.f * __builtin_amdgcn_rcpf(1.f + __builtin_amdgcn_exp2f(-2.88539008f * x)) - 1.f;
}

// fragment-ordered xh address: slab (k/32) of [512 rows x 32 k], tile layout [m/16][lane][8]
__device__ __forceinline__ int haddr(int k, int m) {
  return (k >> 5) * 16384 + (m >> 4) * 512 + ((m & 15) + ((k & 31) >> 3) * 16) * 8 + (k & 7);
}

// counted wait + raw barrier fused in ONE asm so nothing schedules between them.
#define WAITBAR(vm) asm volatile("s_waitcnt vmcnt(" #vm ") lgkmcnt(0)\n\ts_barrier" ::: "memory")

// ============================================================================
// CONDITIONING diagonal kernel — the TLP round. Multi-kernel (dispatch-boundary
// coherence, proven R8/R9), but re-tiled so each CU hosts TWO INDEPENDENT
// blocks (no shared barrier): grid 512 = 4 cells x 128 blocks (M128 x N32h),
// 256 thr/block, LDS = 4-slab ring x 16KB = 64KB -> 2 blocks/CU. When one
// block stalls at WAITBAR its co-resident sibling keeps the matrix pipe fed
// (m114 wave-overlap), and the two independent DMA queues double per-CU
// outstanding staging bytes — the R10/R11-diagnosed wall.
// XCD-clustered decode: xcd=bid&7 (HW round-robin); per XCD each cell gets a
// 4mb x 4nb sub-grid, so mb-siblings share B panels / nb-siblings share the A
// panel in that XCD's L2 (L3 traffic/diag ~190MB instead of ~512MB).
// Slab = A 8KB (M128xK32) + B 8KB (128 gate-cols x K32). Waves 2mg x 2np,
// acc[4][4] full-K (no split-K). Uniform WAITBAR(8) every round (issue-order
// counted, incl. the l==0 ds-write slab-0 case); phantom-clamped tail stages
// keep counts constant; final WAITBAR(0) drains.
// ============================================================================
__global__ __launch_bounds__(256, 2) void lstm_diag2(PP P, int d)
{
  __shared__ f16 lds_a[4][4096];   // 4 x 8KB A-slabs
  __shared__ f16 lds_b[4][4096];   // 4 x 8KB B-slabs
  const int tid = threadIdx.x;
  const int ln = tid & 63, w = tid >> 6;
  const int mg = w >> 1, np = w & 1;         // wave = (row-half, 16-col panel)
  const int bid = blockIdx.x;
  const int xcd = bid & 7;
  const int j   = bid >> 3;                  // 0..63 within XCD
  const int l   = j & 3;                     // cell (layer) on this diagonal
  const int k   = j >> 2;                    // 0..15
  const int mb  = k & 3;                     // M128 row-block
  const int nb  = xcd + 8 * (k >> 2);        // 0..31: N32h col-block (4 per XCD)
  const int m0  = mb * 128;
  const int t = d - l;
  if (t < 0 || t >= T_) return;              // block-uniform

  const int p = t & 1, q = p ^ 1;
  const f16* __restrict__ Wt = P.Wt[l];
  const int KB   = (l == 0) ? KB0 : KBR;
  const int koff = (l == 0) ? 32 : 1024;
  const f16* __restrict__ src = P.xh[l][p];
  f16* __restrict__ selfd     = P.xh[l][q];
  f16* __restrict__ nextd     = (l < 3) ? P.xh[l + 1][p] : nullptr;
  const float* __restrict__ bias4 = P.bias + l * 4096;
  float* __restrict__ cst = P.cst + (size_t)l * 524288;

  // init out[b][t] = bl (consumed by cell 3's atomics 3 dispatches later)
  if (l == 0 && nb == 0 && tid < 128) P.out[(size_t)(m0 + tid) * TT_ + t] = P.blp[0];

  auto stageA = [&](int slot, int kb) {      // 2 gload16/lane (8KB via 512 stores)
    const f16* g0 = src + (size_t)kb * 16384 + mb * 4096;
    gload16(g0 + tid * 8,         &lds_a[slot][tid * 8]);
    gload16(g0 + (tid + 256) * 8, &lds_a[slot][(tid + 256) * 8]);
  };
  auto stageB = [&](int slot, int kb) {      // 2 gload16/lane; panels 2nb, 2nb+1
    #pragma unroll
    for (int jj = 0; jj < 2; ++jj) {
      const int e = tid + jj * 256;          // 0..511 half8-slots
      const int panel = e >> 8, rem = e & 255;
      gload16(Wt + ((size_t)((nb * 2 + panel) * KB + kb)) * 2048 + rem * 8,
              &lds_b[slot][e * 8]);
    }
  };
  auto genA0 = [&]() {                       // l==0 slab 0: x-columns via ds_write
    #pragma unroll
    for (int jj = 0; jj < 2; ++jj) {
      const int idx = tid + jj * 256;
      const int lx = idx & 63, mf = idx >> 6, r = lx & 15, kgrp = lx >> 4;
      const int brow = m0 + mf * 16 + r;
      half8 v;
      #pragma unroll
      for (int z = 0; z < 8; ++z) v[z] = (f16)0.f;
      if (kgrp == 0) {
        v[0] = (f16)P.input[brow * T_ + t];  // conditioning: always real input
        const float* cp = P.cov + ((size_t)brow * TT_ + t) * 7;
        #pragma unroll
        for (int z = 1; z < 8; ++z) v[z] = (f16)cp[z - 1];
      }
      *(half8*)&lds_a[0][idx * 8] = v;
    }
  };

  f32x4 acc[4][4];
  #pragma unroll
  for (int m = 0; m < 4; ++m)
    #pragma unroll
    for (int g = 0; g < 4; ++g) { acc[m][g][0]=0.f; acc[m][g][1]=0.f; acc[m][g][2]=0.f; acc[m][g][3]=0.f; }

  // prologue: 3-slab lookahead. For l==0, B0 is issued FIRST among gloads so
  // round 0's WAITBAR(8) (10 outstanding) provably covers it.
  if (l == 0) {
    genA0();
    stageB(0, 0);
    stageA(1, 1); stageB(1, 1);
    stageA(2, 2); stageB(2, 2);
  } else {
    stageA(0, 0); stageB(0, 0);
    stageA(1, 1); stageB(1, 1);
    stageA(2, 2); stageB(2, 2);
  }

  for (int i = 0; i < KB; ++i) {
    WAITBAR(8);                              // uniform: newest 8 = slabs i+1,i+2
    const int slot = i & 3;
    const half8* A  = (const half8*)&lds_a[slot][0];
    const half8* Bp = (const half8*)&lds_b[slot][0];
    half8 a[4], b[4];
    #pragma unroll
    for (int m = 0; m < 4; ++m) a[m] = A[(mg * 4 + m) * 64 + ln];
    #pragma unroll
    for (int g = 0; g < 4; ++g) b[g] = Bp[(np * 4 + g) * 64 + ln];
    int kn = i + 3; if (kn >= KB) kn = KB - 1;   // phantom-clamped (slot safe: ring-4)
    stageA((i + 3) & 3, kn); stageB((i + 3) & 3, kn);
    __builtin_amdgcn_s_setprio(1);
    #pragma unroll
    for (int m = 0; m < 4; ++m)
      #pragma unroll
      for (int g = 0; g < 4; ++g)
        acc[m][g] = __builtin_amdgcn_mfma_f32_16x16x32_f16(a[m], b[g], acc[m][g], 0, 0, 0);
    __builtin_amdgcn_s_setprio(0);
  }
  WAITBAR(0);                                // drain phantoms before kernel end

  // ---- epilogue: wave (mg,np) owns rows m0+mg*64..+63, h-cols (2nb+np)*16..+15
  const int col = (nb * 2 + np) * 16 + (ln & 15);
  const float bi  = bias4[col];
  const float bff = bias4[1024 + col];
  const float bgg = bias4[2048 + col];
  const float bo  = bias4[3072 + col];
  const float wl  = (l == 3) ? P.Wl[col] : 0.f;
  #pragma unroll
  for (int m = 0; m < 4; ++m) {
    const int rowb = m0 + (mg * 4 + m) * 16 + (ln >> 4) * 4;
    #pragma unroll
    for (int r = 0; r < 4; ++r) {
      const int row = rowb + r;
      float gi = acc[m][0][r] + bi;
      float gf = acc[m][1][r] + bff;
      float gg = acc[m][2][r] + bgg;
      float go = acc[m][3][r] + bo;
      float* cp = cst + (size_t)row * 1024 + col;
      float cn = sigf(gf) * (*cp) + sigf(gi) * tanhf_(gg);
      float h  = sigf(go) * tanhf_(cn);
      *cp = cn;
      f16 hh = (f16)h;
      selfd[haddr(koff + col, row)] = hh;
      if (l < 3) {
        nextd[haddr(col, row)] = hh;
      } else {
        float val = h * wl;
        val += __shfl_xor(val, 1);
        val += __shfl_xor(val, 2);
        val += __shfl_xor(val, 4);
        val += __shfl_xor(val, 8);
        if ((ln & 15) == 0) atomicAdd(P.out + (size_t)row * TT_ + t, val);
      }
    }
  }
}

// ============================================================================
// Small-tile kernel (R4/R8-proven): serial FUTURE phase (t >= 256), 1 cell/dispatch.
// ============================================================================
__global__ __launch_bounds__(512) void lstm_cells(PP P, int d, int lbeg, int lend, int tlim)
{
  __shared__ f16 lds[NSLOT][6144];
  const int tid = threadIdx.x;
  const int ln = tid & 63, w = tid >> 6;
  const int mg = w & 1, kg = w >> 1;
  const int nb = blockIdx.x & 63, mb = blockIdx.x >> 6;
  const int m0 = mb * 128, n0 = nb * 16;

  for (int l = lbeg; l <= lend; ++l) {
    const int t = d - l;
    if (t < 0 || t >= tlim) continue;

    const int p = t & 1, q = p ^ 1;
    const f16* __restrict__ Wt = P.Wt[l];
    const int KB   = (l == 0) ? KB0 : KBR;
    const int mode = (l == 0) ? 0 : ((l == 3) ? 2 : 1);
    const int koff = (l == 0) ? 32 : 1024;
    const f16* __restrict__ src   = P.xh[l][p];
    f16* __restrict__ selfd       = P.xh[l][q];
    f16* __restrict__ nextd       = (l < 3) ? P.xh[l + 1][p] : nullptr;
    const float* __restrict__ bias4 = P.bias + l * 4096;
    float* __restrict__ cst = P.cst + (size_t)l * 524288;

    if (mode == 0 && nb == 0 && tid < 128) P.out[(size_t)(m0 + tid) * TT_ + t] = P.blp[0];

    auto stage_slab = [&](int slot, int kb) {
      if (mode == 0 && kb == 0) {
        int mf = tid >> 6, r = ln & 15, kgrp = ln >> 4;
        int brow = m0 + mf * 16 + r;
        half8 v;
        #pragma unroll
        for (int jj = 0; jj < 8; ++jj) v[jj] = (f16)0.f;
        if (kgrp == 0) {
          float x0 = (t < T_) ? P.input[brow * T_ + t] : P.out[(size_t)brow * TT_ + (t - 1)];
          v[0] = (f16)x0;
          const float* cp = P.cov + ((size_t)brow * TT_ + t) * 7;
          #pragma unroll
          for (int jj = 1; jj < 8; ++jj) v[jj] = (f16)cp[jj - 1];
        }
        *(half8*)&lds[slot][tid * 8] = v;
      } else {
        gload16(src + (size_t)kb * 16384 + mb * 4096 + tid * 8, &lds[slot][tid * 8]);
      }
      if (tid < 256)
        gload16(Wt + ((size_t)(nb * KB + kb)) * 2048 + tid * 8, &lds[slot][4096 + tid * 8]);
    };
    auto stage_round = [&](int r) {
      int base = (r % 3) * 4;
      #pragma unroll
      for (int jj = 0; jj < 4; ++jj) {
        int kb = r * 4 + jj;
        if (kb >= KB) kb = KB - 1;
        stage_slab(base + jj, kb);
      }
    };

    f32x4 acc[4][4];
    #pragma unroll
    for (int m = 0; m < 4; ++m)
      #pragma unroll
      for (int g = 0; g < 4; ++g) { acc[m][g][0]=0.f; acc[m][g][1]=0.f; acc[m][g][2]=0.f; acc[m][g][3]=0.f; }

    const int R = (KB + 3) >> 2;
    stage_round(0); stage_round(1);
    for (int i = 0; i < R; ++i) {
      if (i < R - 1) { if (w < 4) WAITBAR(8); else WAITBAR(4); }
      else           { WAITBAR(0); }
      const int kb = i * 4 + kg;
      const int slot = (i % 3) * 4 + kg;
      const half8* A  = (const half8*)&lds[slot][0];
      const half8* Bp = (const half8*)&lds[slot][4096];
      const bool live = (kb < KB);
      half8 a0, a1, a2, a3, b0, b1, b2, b3;
      if (live) {
        a0 = A[(mg * 4 + 0) * 64 + ln];
        a1 = A[(mg * 4 + 1) * 64 + ln];
        a2 = A[(mg * 4 + 2) * 64 + ln];
        a3 = A[(mg * 4 + 3) * 64 + ln];
        b0 = Bp[ln]; b1 = Bp[64 + ln]; b2 = Bp[128 + ln]; b3 = Bp[192 + ln];
      }
      if (i + 2 < R) stage_round(i + 2);
      if (live) {
        acc[0][0] = __builtin_amdgcn_mfma_f32_16x16x32_f16(a0, b0, acc[0][0], 0, 0, 0);
        acc[0][1] = __builtin_amdgcn_mfma_f32_16x16x32_f16(a0, b1, acc[0][1], 0, 0, 0);
        acc[0][2] = __builtin_amdgcn_mfma_f32_16x16x32_f16(a0, b2, acc[0][2], 0, 0, 0);
        acc[0][3] = __builtin_amdgcn_mfma_f32_16x16x32_f16(a0, b3, acc[0][3], 0, 0, 0);
        acc[1][0] = __builtin_amdgcn_mfma_f32_16x16x32_f16(a1, b0, acc[1][0], 0, 0, 0);
        acc[1][1] = __builtin_amdgcn_mfma_f32_16x16x32_f16(a1, b1, acc[1][1], 0, 0, 0);
        acc[1][2] = __builtin_amdgcn_mfma_f32_16x16x32_f16(a1, b2, acc[1][2], 0, 0, 0);
        acc[1][3] = __builtin_amdgcn_mfma_f32_16x16x32_f16(a1, b3, acc[1][3], 0, 0, 0);
        acc[2][0] = __builtin_amdgcn_mfma_f32_16x16x32_f16(a2, b0, acc[2][0], 0, 0, 0);
        acc[2][1] = __builtin_amdgcn_mfma_f32_16x16x32_f16(a2, b1, acc[2][1], 0, 0, 0);
        acc[2][2] = __builtin_amdgcn_mfma_f32_16x16x32_f16(a2, b2, acc[2][2], 0, 0, 0);
        acc[2][3] = __builtin_amdgcn_mfma_f32_16x16x32_f16(a2, b3, acc[2][3], 0, 0, 0);
        acc[3][0] = __builtin_amdgcn_mfma_f32_16x16x32_f16(a3, b0, acc[3][0], 0, 0, 0);
        acc[3][1] = __builtin_amdgcn_mfma_f32_16x16x32_f16(a3, b1, acc[3][1], 0, 0, 0);
        acc[3][2] = __builtin_amdgcn_mfma_f32_16x16x32_f16(a3, b2, acc[3][2], 0, 0, 0);
        acc[3][3] = __builtin_amdgcn_mfma_f32_16x16x32_f16(a3, b3, acc[3][3], 0, 0, 0);
      }
    }

    __syncthreads();
    float* red = (float*)&lds[0][0];
    #pragma unroll
    for (int m = 0; m < 4; ++m)
      #pragma unroll
      for (int g = 0; g < 4; ++g)
        *(f32x4*)&red[w * 4096 + (m * 4 + g) * 256 + ln * 4] = acc[m][g];
    __syncthreads();
    f32x4 facc[4];
    #pragma unroll
    for (int g = 0; g < 4; ++g) { facc[g][0]=0.f; facc[g][1]=0.f; facc[g][2]=0.f; facc[g][3]=0.f; }
    const int mgw = w >> 2, mlw = w & 3;
    #pragma unroll
    for (int kg2 = 0; kg2 < 4; ++kg2) {
      const int wsrc = kg2 * 2 + mgw;
      #pragma unroll
      for (int g = 0; g < 4; ++g) {
        f32x4 pv = *(const f32x4*)&red[wsrc * 4096 + (mlw * 4 + g) * 256 + ln * 4];
        facc[g][0] += pv[0]; facc[g][1] += pv[1]; facc[g][2] += pv[2]; facc[g][3] += pv[3];
      }
    }
    __syncthreads();

    const int col = n0 + (ln & 15);
    const int rowb = m0 + w * 16 + (ln >> 4) * 4;
    const float bi  = bias4[col];
    const float bff = bias4[1024 + col];
    const float bgg = bias4[2048 + col];
    const float bo  = bias4[3072 + col];
    const float wl  = (mode == 2) ? P.Wl[col] : 0.f;
    #pragma unroll
    for (int r = 0; r < 4; ++r) {
      const int row = rowb + r;
      float gi = facc[0][r] + bi;
      float gf = facc[1][r] + bff;
      float gg = facc[2][r] + bgg;
      float go = facc[3][r] + bo;
      float* cp = cst + (size_t)row * 1024 + col;
      float cn = sigf(gf) * (*cp) + sigf(gi) * tanhf_(gg);
      float h  = sigf(go) * tanhf_(cn);
      *cp = cn;
      f16 hh = (f16)h;
      selfd[haddr(koff + col, row)] = hh;
      if (mode != 2) {
        nextd[haddr(col, row)] = hh;
      } else {
        float val = h * wl;
        val += __shfl_xor(val, 1);
        val += __shfl_xor(val, 2);
        val += __shfl_xor(val, 4);
        val += __shfl_xor(val, 8);
        if ((ln & 15) == 0) atomicAdd(P.out + (size_t)row * TT_ + t, val);
      }
    }
  }
}

__global__ void zero_ws(uint4v* pz, int n)   // zero xh buffers + cell state
{
  int i = blockIdx.x * 256 + threadIdx.x;
  if (i < n) { uint4v z; z[0] = 0u; z[1] = 0u; z[2] = 0u; z[3] = 0u; pz[i] = z; }
}

__global__ void pack_weights(const float* __restrict__ Wih0, const float* __restrict__ Whh0,
                             const float* __restrict__ Wihr, const float* __restrict__ Whhr,
                             f16* __restrict__ Wt0, f16* __restrict__ Wt1,
                             f16* __restrict__ Wt2, f16* __restrict__ Wt3)
{
  const int layer = blockIdx.y;
  const size_t e = (size_t)blockIdx.x * 256 + threadIdx.x;
  const int KB = layer ? KBR : KB0;
  if (e >= (size_t)64 * KB * 2048) return;
  const int panel = (int)(e >> 11), win = (int)(e & 2047);
  const int g = win >> 9, lane = (win >> 3) & 63, j = win & 7;
  const int nb = panel / KB, kb = panel - nb * KB;
  const int n = nb * 16 + (lane & 15);
  const int k = kb * 32 + (lane >> 4) * 8 + j;
  const int jr = g * 1024 + n;                       // row in [4H][*] weight (gate-major)
  float v;
  if (layer == 0) {
    if (k < 8)       v = Wih0[jr * 8 + k];
    else if (k < 32) v = 0.f;
    else             v = Whh0[(size_t)jr * 1024 + (k - 32)];
  } else {
    const size_t base = (size_t)(layer - 1) * 4096 * 1024 + (size_t)jr * 1024;
    v = (k < 1024) ? Wihr[base + k] : Whhr[base + (k - 1024)];
  }
  f16 hv = (f16)v;
  if      (layer == 0) Wt0[e] = hv;
  else if (layer == 1) Wt1[e] = hv;
  else if (layer == 2) Wt2[e] = hv;
  else                 Wt3[e] = hv;
}

__global__ void pack_bias(const float* __restrict__ bih0, const float* __restrict__ bhh0,
                          const float* __restrict__ bihr, const float* __restrict__ bhhr,
                          float* __restrict__ bias)
{
  const int idx = blockIdx.x * 256 + threadIdx.x;    // 16384 = 4 layers x 4096
  const int lyr = idx >> 12, j = idx & 4095;
  bias[idx] = (lyr == 0) ? (bih0[j] + bhh0[j])
                         : (bihr[(lyr - 1) * 4096 + j] + bhhr[(lyr - 1) * 4096 + j]);
}

extern "C" void kernel_launch(void* const* d_in, const int* in_sizes, int n_in,
                              void* d_out, int out_size, void* d_ws, size_t ws_size,
                              hipStream_t stream)
{
  const float* input = (const float*)d_in[0];
  const float* cov   = (const float*)d_in[1];
  const float* Wih0  = (const float*)d_in[2];
  const float* Whh0  = (const float*)d_in[3];
  const float* bih0  = (const float*)d_in[4];
  const float* bhh0  = (const float*)d_in[5];
  const float* Wihr  = (const float*)d_in[6];
  const float* Whhr  = (const float*)d_in[7];
  const float* bihr  = (const float*)d_in[8];
  const float* bhhr  = (const float*)d_in[9];
  const float* Wl    = (const float*)d_in[10];
  const float* blp   = (const float*)d_in[11];
  float* out = (float*)d_out;
  char* ws = (char*)d_ws;

  // workspace layout (bytes): unchanged from R8-R12.
  // xh + c zeroed per call by zero_ws (same-call, stream-ordered): no cross-call state.
  const size_t XH0 = 1081344, XHR = 2097152;
  PP Pv;
  Pv.xh[0][0] = (f16*)(ws);            Pv.xh[0][1] = (f16*)(ws + XH0);
  Pv.xh[1][0] = (f16*)(ws + 2162688);  Pv.xh[1][1] = (f16*)(ws + 2162688 + XHR);
  Pv.xh[2][0] = (f16*)(ws + 6356992);  Pv.xh[2][1] = (f16*)(ws + 6356992 + XHR);
  Pv.xh[3][0] = (f16*)(ws + 10551296); Pv.xh[3][1] = (f16*)(ws + 10551296 + XHR);
  Pv.cst     = (float*)(ws + 14745600);
  float* bias = (float*)(ws + 23134208);
  f16* Wt0 = (f16*)(ws + 23199744);
  f16* Wt1 = (f16*)(ws + 31850496);
  f16* Wt2 = (f16*)(ws + 48627712);
  f16* Wt3 = (f16*)(ws + 65404928);
  Pv.Wt[0] = Wt0; Pv.Wt[1] = Wt1; Pv.Wt[2] = Wt2; Pv.Wt[3] = Wt3;
  Pv.bias = bias; Pv.input = input; Pv.cov = cov;
  Pv.Wl = Wl; Pv.blp = blp; Pv.out = out;

  pack_weights<<<dim3(32768, 4), 256, 0, stream>>>(Wih0, Whh0, Wihr, Whhr, Wt0, Wt1, Wt2, Wt3);
  pack_bias<<<64, 256, 0, stream>>>(bih0, bhh0, bihr, bhhr, bias);
  zero_ws<<<5648, 256, 0, stream>>>((uint4v*)ws, 23134208 / 16);

  // Conditioning (t < 256): anti-diagonal wavefront; 512 blocks = 4 cells x 128,
  // 2 independent blocks per CU (TLP latency hiding).
  for (int dg = 0; dg <= 258; ++dg)
    lstm_diag2<<<512, 256, 0, stream>>>(Pv, dg);
  // Future (t >= 256): out-feedback serializes; one small-tile cell per dispatch.
  for (int t = T_; t < TT_; ++t)
    for (int l = 0; l < 4; ++l)
      lstm_cells<<<256, 512, 0, stream>>>(Pv, t + l, l, l, TT_);
}